// Round 3
// baseline (494.645 us; speedup 1.0000x reference)
//
#include <hip/hip_runtime.h>

// DiceLoss: pred [3,1,192,192,192] f32, target same, weight [3] f32 -> scalar f32
// loss = (1/B) * sum_b [ 1 - (2*sum(p*t)*w + 1) / ((sum(p)+sum(t))*w + 1) ],
// p = sigmoid(pred). Single fused kernel: per-block partials + last-block
// ticket finalize (saves the 2nd launch + gap).

constexpr int B_BATCH  = 3;
constexpr int D3       = 192 * 192 * 192;     // 7,077,888
constexpr int N4       = D3 / 4;              // 1,769,472 float4 per batch
constexpr int BLK      = 256;
constexpr int ITERS    = 6;                   // chunk = 1536 float4
constexpr int CHUNK    = BLK * ITERS;
constexpr int BLOCKS_X = N4 / CHUNK;          // 1152 (exact)
constexpr int GRID     = BLOCKS_X * B_BATCH;  // 3456 = 13.5 blocks/CU

__device__ __forceinline__ float fsigmoid(float x) {
    return __builtin_amdgcn_rcpf(1.f + __expf(-x));
}

// ws layout: [0..3] ticket (int, memset to 0 per call); partials at +64B:
// 9 planes of BLOCKS_X floats, plane c9 = b*3 + c (c: 0=sum p, 1=sum t, 2=sum p*t)
__global__ __launch_bounds__(BLK) void dice_fused(
    const float* __restrict__ pred,
    const float* __restrict__ target,
    const float* __restrict__ weight,
    float* __restrict__ out,
    int* __restrict__ ticket,
    float* __restrict__ part)
{
    const int b = blockIdx.y;
    const float4* __restrict__ p4 =
        reinterpret_cast<const float4*>(pred) + (size_t)b * N4;
    const float4* __restrict__ t4 =
        reinterpret_cast<const float4*>(target) + (size_t)b * N4;

    const int base = blockIdx.x * CHUNK + threadIdx.x;

    // Batch all loads first: 12 dwordx4 in flight per thread.
    float4 pv[ITERS], tv[ITERS];
    #pragma unroll
    for (int j = 0; j < ITERS; ++j) pv[j] = p4[base + j * BLK];
    #pragma unroll
    for (int j = 0; j < ITERS; ++j) tv[j] = t4[base + j * BLK];

    float sp[2]  = {0.f, 0.f};
    float st[2]  = {0.f, 0.f};
    float spt[2] = {0.f, 0.f};
    #pragma unroll
    for (int j = 0; j < ITERS; ++j) {
        float s0 = fsigmoid(pv[j].x);
        float s1 = fsigmoid(pv[j].y);
        float s2 = fsigmoid(pv[j].z);
        float s3 = fsigmoid(pv[j].w);
        const int a = j & 1;
        sp[a]  += (s0 + s1) + (s2 + s3);
        st[a]  += (tv[j].x + tv[j].y) + (tv[j].z + tv[j].w);
        spt[a] += (s0 * tv[j].x + s1 * tv[j].y) + (s2 * tv[j].z + s3 * tv[j].w);
    }
    float rsp  = sp[0]  + sp[1];
    float rst  = st[0]  + st[1];
    float rspt = spt[0] + spt[1];

    // wave64 butterfly reduce
    #pragma unroll
    for (int off = 32; off > 0; off >>= 1) {
        rsp  += __shfl_down(rsp,  off);
        rst  += __shfl_down(rst,  off);
        rspt += __shfl_down(rspt, off);
    }

    __shared__ float red[4][3];
    const int wave = threadIdx.x >> 6;
    const int lane = threadIdx.x & 63;
    if (lane == 0) {
        red[wave][0] = rsp;
        red[wave][1] = rst;
        red[wave][2] = rspt;
    }
    __syncthreads();
    if (threadIdx.x == 0) {
        float a0 = (red[0][0] + red[1][0]) + (red[2][0] + red[3][0]);
        float a1 = (red[0][1] + red[1][1]) + (red[2][1] + red[3][1]);
        float a2 = (red[0][2] + red[1][2]) + (red[2][2] + red[3][2]);
        part[(b * 3 + 0) * BLOCKS_X + blockIdx.x] = a0;
        part[(b * 3 + 1) * BLOCKS_X + blockIdx.x] = a1;
        part[(b * 3 + 2) * BLOCKS_X + blockIdx.x] = a2;
    }

    // last-block ticket
    __shared__ int is_last;
    __threadfence();  // release: partial stores visible before ticket bump
    if (threadIdx.x == 0)
        is_last = (atomicAdd(ticket, 1) == GRID - 1);
    __syncthreads();
    if (!is_last) return;

    __threadfence();  // acquire
    volatile const float* vp = part;  // bypass L1 (stale lines across replays)

    __shared__ float sums[9];
    // wave w reduces planes w, w+4, w+8 (<9)
    for (int c9 = wave; c9 < 9; c9 += 4) {
        float s = 0.f;
        #pragma unroll
        for (int i = 0; i < BLOCKS_X / 64; ++i)
            s += vp[c9 * BLOCKS_X + i * 64 + lane];
        #pragma unroll
        for (int off = 32; off > 0; off >>= 1)
            s += __shfl_down(s, off);
        if (lane == 0) sums[c9] = s;
    }
    __syncthreads();

    if (threadIdx.x == 0) {
        float loss = 0.f;
        #pragma unroll
        for (int bb = 0; bb < B_BATCH; ++bb) {
            float wgt  = weight[bb];
            float ssp  = sums[bb * 3 + 0];
            float sst  = sums[bb * 3 + 1];
            float sspt = sums[bb * 3 + 2];
            float dice = (2.f * sspt * wgt + 1.f) / ((ssp + sst) * wgt + 1.f);
            loss += 1.f - dice;
        }
        out[0] = loss / (float)B_BATCH;
    }
}

extern "C" void kernel_launch(void* const* d_in, const int* in_sizes, int n_in,
                              void* d_out, int out_size, void* d_ws, size_t ws_size,
                              hipStream_t stream) {
    const float* pred   = (const float*)d_in[0];
    const float* target = (const float*)d_in[1];
    const float* weight = (const float*)d_in[2];
    float* out   = (float*)d_out;
    int*   ticket = (int*)d_ws;
    float* part  = (float*)((char*)d_ws + 64);  // 9*1152*4 = 41,472 B partials

    hipMemsetAsync(d_ws, 0, 4, stream);  // reset ticket each call (graph-safe)

    dim3 grid(BLOCKS_X, B_BATCH);
    dice_fused<<<grid, BLK, 0, stream>>>(pred, target, weight, out, ticket, part);
}

// Round 4
// 88.205 us; speedup vs baseline: 5.6079x; 5.6079x over previous
//
#include <hip/hip_runtime.h>

// DiceLoss: pred [3,1,192,192,192] f32, target same, weight [3] f32 -> scalar f32
// loss = (1/B) * sum_b [ 1 - (2*sum(p*t)*w + 1) / ((sum(p)+sum(t))*w + 1) ],
// p = sigmoid(pred).
//
// Single fused kernel. Per-block partials are published with DEVICE-SCOPE
// atomicAdd (coherent point; no __threadfence broadcast -- R3 showed per-thread
// device fences cost ~600us in L2 writeback traffic). Last block (ticket) reads
// the 9 sums back with returning atomics and computes the scalar.

constexpr int B_BATCH  = 3;
constexpr int D3       = 192 * 192 * 192;      // 7,077,888
constexpr int N4       = D3 / 4;               // 1,769,472 float4 per batch
constexpr int BLK      = 256;
constexpr int ITERS    = 12;                   // exact: 256*12*576 == N4
constexpr int BLOCKS_X = N4 / (BLK * ITERS);   // 576
constexpr int GRID     = BLOCKS_X * B_BATCH;   // 1728 blocks (6.75/CU)

__device__ __forceinline__ float fsigmoid(float x) {
    return __builtin_amdgcn_rcpf(1.f + __expf(-x));
}

// ws layout (memset to 0 per call, 640 bytes):
//   [0]            : int ticket
//   [64 + c9*64]   : float accumulator for plane c9 = b*3 + c  (64B padded)
__global__ __launch_bounds__(BLK) void dice_fused(
    const float* __restrict__ pred,
    const float* __restrict__ target,
    const float* __restrict__ weight,
    float* __restrict__ out,
    int* __restrict__ ticket,
    float* __restrict__ sums /* padded: index c9*16 */)
{
    const int b = blockIdx.y;
    const float4* __restrict__ p4 =
        reinterpret_cast<const float4*>(pred) + (size_t)b * N4;
    const float4* __restrict__ t4 =
        reinterpret_cast<const float4*>(target) + (size_t)b * N4;

    const int base = blockIdx.x * (BLK * ITERS) + threadIdx.x;

    float sp[4]  = {0.f, 0.f, 0.f, 0.f};
    float st[4]  = {0.f, 0.f, 0.f, 0.f};
    float spt[4] = {0.f, 0.f, 0.f, 0.f};

    #pragma unroll
    for (int j = 0; j < ITERS; ++j) {
        float4 pv = p4[base + j * BLK];
        float4 tv = t4[base + j * BLK];
        float s0 = fsigmoid(pv.x);
        float s1 = fsigmoid(pv.y);
        float s2 = fsigmoid(pv.z);
        float s3 = fsigmoid(pv.w);
        const int a = j & 3;
        sp[a]  += (s0 + s1) + (s2 + s3);
        st[a]  += (tv.x + tv.y) + (tv.z + tv.w);
        spt[a] += (s0 * tv.x + s1 * tv.y) + (s2 * tv.z + s3 * tv.w);
    }

    float rsp  = (sp[0]  + sp[1])  + (sp[2]  + sp[3]);
    float rst  = (st[0]  + st[1])  + (st[2]  + st[3]);
    float rspt = (spt[0] + spt[1]) + (spt[2] + spt[3]);

    #pragma unroll
    for (int off = 32; off > 0; off >>= 1) {
        rsp  += __shfl_down(rsp,  off);
        rst  += __shfl_down(rst,  off);
        rspt += __shfl_down(rspt, off);
    }

    __shared__ float red[4][3];
    __shared__ int is_last;
    const int wave = threadIdx.x >> 6;
    const int lane = threadIdx.x & 63;
    if (lane == 0) {
        red[wave][0] = rsp;
        red[wave][1] = rst;
        red[wave][2] = rspt;
    }
    __syncthreads();

    if (threadIdx.x == 0) {
        float a0 = (red[0][0] + red[1][0]) + (red[2][0] + red[3][0]);
        float a1 = (red[0][1] + red[1][1]) + (red[2][1] + red[3][1]);
        float a2 = (red[0][2] + red[1][2]) + (red[2][2] + red[3][2]);
        // Device-scope atomics land at the coherent point -- no fences needed.
        float o0 = atomicAdd(&sums[(b * 3 + 0) * 16], a0);
        float o1 = atomicAdd(&sums[(b * 3 + 1) * 16], a1);
        float o2 = atomicAdd(&sums[(b * 3 + 2) * 16], a2);
        // Force the waitcnt on the returning atomics before bumping the ticket
        // (orders this block's sum-adds before its ticket increment).
        asm volatile("" :: "v"(o0), "v"(o1), "v"(o2));
        int prev = __hip_atomic_fetch_add(ticket, 1, __ATOMIC_ACQ_REL,
                                          __HIP_MEMORY_SCOPE_AGENT);
        is_last = (prev == GRID - 1);
    }
    __syncthreads();
    if (!is_last) return;

    if (threadIdx.x == 0) {
        float tot[9];
        #pragma unroll
        for (int c9 = 0; c9 < 9; ++c9)
            tot[c9] = atomicAdd(&sums[c9 * 16], 0.0f);  // coherent read-back
        float loss = 0.f;
        #pragma unroll
        for (int bb = 0; bb < B_BATCH; ++bb) {
            float wgt  = weight[bb];
            float ssp  = tot[bb * 3 + 0];
            float sst  = tot[bb * 3 + 1];
            float sspt = tot[bb * 3 + 2];
            float dice = (2.f * sspt * wgt + 1.f) / ((ssp + sst) * wgt + 1.f);
            loss += 1.f - dice;
        }
        out[0] = loss / (float)B_BATCH;
    }
}

extern "C" void kernel_launch(void* const* d_in, const int* in_sizes, int n_in,
                              void* d_out, int out_size, void* d_ws, size_t ws_size,
                              hipStream_t stream) {
    const float* pred   = (const float*)d_in[0];
    const float* target = (const float*)d_in[1];
    const float* weight = (const float*)d_in[2];
    float* out    = (float*)d_out;
    int*   ticket = (int*)d_ws;
    float* sums   = (float*)((char*)d_ws + 64);

    hipMemsetAsync(d_ws, 0, 640, stream);  // ticket + 9 padded accumulators

    dim3 grid(BLOCKS_X, B_BATCH);
    dice_fused<<<grid, BLK, 0, stream>>>(pred, target, weight, out, ticket, sums);
}

// Round 5
// 43.708 us; speedup vs baseline: 11.3172x; 2.0181x over previous
//
#include <hip/hip_runtime.h>

// DiceLoss: pred [3,1,192,192,192] f32, target same, weight [3] f32 -> scalar f32
// loss = (1/B) * sum_b [ 1 - (2*sum(p*t)*w + 1) / ((sum(p)+sum(t))*w + 1) ],
// p = sigmoid(pred).
//
// Two kernels (R3/R4 showed in-kernel cross-XCD publication -- fences or
// agent-scope atomics -- costs 60..460us in L2 maintenance traffic; a second
// launch costs ~4us). Kernel1 streams with explicit 8-deep load batching.

constexpr int B_BATCH  = 3;
constexpr int D3       = 192 * 192 * 192;      // 7,077,888
constexpr int N4       = D3 / 4;               // 1,769,472 float4 per batch
constexpr int BLK      = 256;
constexpr int ITERS    = 8;                    // exact: 256*8*864 == N4
constexpr int GROUP    = 4;                    // 8 dwordx4 in flight per group
constexpr int BLOCKS_X = N4 / (BLK * ITERS);   // 864 -> grid 2592 (10.1/CU)

__device__ __forceinline__ float fsigmoid(float x) {
    return __builtin_amdgcn_rcpf(1.f + __expf(-x));
}

__global__ __launch_bounds__(BLK) void dice_partial(
    const float* __restrict__ pred,
    const float* __restrict__ target,
    float* __restrict__ part /* plane-major [9][BLOCKS_X] */)
{
    const int b = blockIdx.y;
    const float4* __restrict__ p4 =
        reinterpret_cast<const float4*>(pred) + (size_t)b * N4;
    const float4* __restrict__ t4 =
        reinterpret_cast<const float4*>(target) + (size_t)b * N4;

    const int base = blockIdx.x * (BLK * ITERS) + threadIdx.x;

    float sp[GROUP]  = {0.f, 0.f, 0.f, 0.f};
    float st[GROUP]  = {0.f, 0.f, 0.f, 0.f};
    float spt[GROUP] = {0.f, 0.f, 0.f, 0.f};

    #pragma unroll
    for (int g = 0; g < ITERS / GROUP; ++g) {
        // Issue all 8 loads of this group before any use (8 dwordx4 in flight).
        float4 pv[GROUP], tv[GROUP];
        #pragma unroll
        for (int k = 0; k < GROUP; ++k)
            pv[k] = p4[base + (g * GROUP + k) * BLK];
        #pragma unroll
        for (int k = 0; k < GROUP; ++k)
            tv[k] = t4[base + (g * GROUP + k) * BLK];
        #pragma unroll
        for (int k = 0; k < GROUP; ++k) {
            float s0 = fsigmoid(pv[k].x);
            float s1 = fsigmoid(pv[k].y);
            float s2 = fsigmoid(pv[k].z);
            float s3 = fsigmoid(pv[k].w);
            sp[k]  += (s0 + s1) + (s2 + s3);
            st[k]  += (tv[k].x + tv[k].y) + (tv[k].z + tv[k].w);
            spt[k] += (s0 * tv[k].x + s1 * tv[k].y) + (s2 * tv[k].z + s3 * tv[k].w);
        }
    }

    float rsp  = (sp[0]  + sp[1])  + (sp[2]  + sp[3]);
    float rst  = (st[0]  + st[1])  + (st[2]  + st[3]);
    float rspt = (spt[0] + spt[1]) + (spt[2] + spt[3]);

    // wave64 butterfly reduce
    #pragma unroll
    for (int off = 32; off > 0; off >>= 1) {
        rsp  += __shfl_down(rsp,  off);
        rst  += __shfl_down(rst,  off);
        rspt += __shfl_down(rspt, off);
    }

    __shared__ float red[4][3];
    const int wave = threadIdx.x >> 6;
    const int lane = threadIdx.x & 63;
    if (lane == 0) {
        red[wave][0] = rsp;
        red[wave][1] = rst;
        red[wave][2] = rspt;
    }
    __syncthreads();
    if (threadIdx.x == 0) {
        float a0 = (red[0][0] + red[1][0]) + (red[2][0] + red[3][0]);
        float a1 = (red[0][1] + red[1][1]) + (red[2][1] + red[3][1]);
        float a2 = (red[0][2] + red[1][2]) + (red[2][2] + red[3][2]);
        part[(b * 3 + 0) * BLOCKS_X + blockIdx.x] = a0;  // sum p
        part[(b * 3 + 1) * BLOCKS_X + blockIdx.x] = a1;  // sum t
        part[(b * 3 + 2) * BLOCKS_X + blockIdx.x] = a2;  // sum p*t
    }
}

// One block, 4 waves; wave w reduces planes w, w+4, w+8 (<9); thread 0 finishes.
__global__ __launch_bounds__(256) void dice_final(
    const float* __restrict__ part /* [9][BLOCKS_X] */,
    const float* __restrict__ weight,
    float* __restrict__ out)
{
    __shared__ float sums[9];
    const int wave = threadIdx.x >> 6;
    const int lane = threadIdx.x & 63;

    for (int c9 = wave; c9 < 9; c9 += 4) {
        float s = 0.f;
        for (int i = lane; i < BLOCKS_X; i += 64)
            s += part[c9 * BLOCKS_X + i];
        #pragma unroll
        for (int off = 32; off > 0; off >>= 1)
            s += __shfl_down(s, off);
        if (lane == 0) sums[c9] = s;
    }
    __syncthreads();

    if (threadIdx.x == 0) {
        float loss = 0.f;
        #pragma unroll
        for (int bb = 0; bb < B_BATCH; ++bb) {
            float wgt  = weight[bb];
            float ssp  = sums[bb * 3 + 0];
            float sst  = sums[bb * 3 + 1];
            float sspt = sums[bb * 3 + 2];
            float dice = (2.f * sspt * wgt + 1.f) / ((ssp + sst) * wgt + 1.f);
            loss += 1.f - dice;
        }
        out[0] = loss / (float)B_BATCH;
    }
}

extern "C" void kernel_launch(void* const* d_in, const int* in_sizes, int n_in,
                              void* d_out, int out_size, void* d_ws, size_t ws_size,
                              hipStream_t stream) {
    const float* pred   = (const float*)d_in[0];
    const float* target = (const float*)d_in[1];
    const float* weight = (const float*)d_in[2];
    float* out  = (float*)d_out;
    float* part = (float*)d_ws;  // 9 * 864 * 4 = 31,104 bytes

    dim3 grid(BLOCKS_X, B_BATCH);
    dice_partial<<<grid, BLK, 0, stream>>>(pred, target, part);
    dice_final<<<1, 256, 0, stream>>>(part, weight, out);
}

// Round 6
// 32.456 us; speedup vs baseline: 15.2407x; 1.3467x over previous
//
#include <hip/hip_runtime.h>

// DiceLoss: pred [3,1,192,192,192] f32, target same, weight [3] f32 -> scalar f32
// loss = (1/B) * sum_b [ 1 - (2*sum(p*t)*w + 1) / ((sum(p)+sum(t))*w + 1) ],
// p = sigmoid(pred).
//
// Two-kernel structure (R3/R4: any in-kernel cross-XCD publication -- fences or
// agent-scope atomics -- costs 60..460us in L2 maintenance; a 2nd launch ~4us).
// R2 config restored: 1728 blocks ALL co-resident (<= 2048 = 8/CU cap; R5's
// 2592-block grid added a 21% second-round tail). Kernel1 is BW-bound at
// ~6.1 TB/s delivered == the measured float4-copy ceiling.

constexpr int B_BATCH  = 3;
constexpr int D3       = 192 * 192 * 192;      // 7,077,888
constexpr int N4       = D3 / 4;               // 1,769,472 float4 per batch
constexpr int BLK      = 256;
constexpr int ITERS    = 12;                   // exact: 256*12*576 == N4
constexpr int BLOCKS_X = N4 / (BLK * ITERS);   // 576 -> grid 1728, 6.75/CU

__device__ __forceinline__ float fsigmoid(float x) {
    return __builtin_amdgcn_rcpf(1.f + __expf(-x));
}

__global__ __launch_bounds__(BLK) void dice_partial(
    const float* __restrict__ pred,
    const float* __restrict__ target,
    float* __restrict__ part /* plane-major [9][BLOCKS_X] */)
{
    const int b = blockIdx.y;
    const float4* __restrict__ p4 =
        reinterpret_cast<const float4*>(pred) + (size_t)b * N4;
    const float4* __restrict__ t4 =
        reinterpret_cast<const float4*>(target) + (size_t)b * N4;

    const int base = blockIdx.x * (BLK * ITERS) + threadIdx.x;

    float sp[4]  = {0.f, 0.f, 0.f, 0.f};
    float st[4]  = {0.f, 0.f, 0.f, 0.f};
    float spt[4] = {0.f, 0.f, 0.f, 0.f};

    #pragma unroll
    for (int j = 0; j < ITERS; ++j) {
        float4 pv = p4[base + j * BLK];
        float4 tv = t4[base + j * BLK];
        float s0 = fsigmoid(pv.x);
        float s1 = fsigmoid(pv.y);
        float s2 = fsigmoid(pv.z);
        float s3 = fsigmoid(pv.w);
        const int a = j & 3;
        sp[a]  += (s0 + s1) + (s2 + s3);
        st[a]  += (tv.x + tv.y) + (tv.z + tv.w);
        spt[a] += (s0 * tv.x + s1 * tv.y) + (s2 * tv.z + s3 * tv.w);
    }

    float rsp  = (sp[0]  + sp[1])  + (sp[2]  + sp[3]);
    float rst  = (st[0]  + st[1])  + (st[2]  + st[3]);
    float rspt = (spt[0] + spt[1]) + (spt[2] + spt[3]);

    // wave64 butterfly reduce
    #pragma unroll
    for (int off = 32; off > 0; off >>= 1) {
        rsp  += __shfl_down(rsp,  off);
        rst  += __shfl_down(rst,  off);
        rspt += __shfl_down(rspt, off);
    }

    __shared__ float red[4][3];
    const int wave = threadIdx.x >> 6;
    const int lane = threadIdx.x & 63;
    if (lane == 0) {
        red[wave][0] = rsp;
        red[wave][1] = rst;
        red[wave][2] = rspt;
    }
    __syncthreads();
    if (threadIdx.x == 0) {
        float a0 = (red[0][0] + red[1][0]) + (red[2][0] + red[3][0]);
        float a1 = (red[0][1] + red[1][1]) + (red[2][1] + red[3][1]);
        float a2 = (red[0][2] + red[1][2]) + (red[2][2] + red[3][2]);
        part[(b * 3 + 0) * BLOCKS_X + blockIdx.x] = a0;  // sum p
        part[(b * 3 + 1) * BLOCKS_X + blockIdx.x] = a1;  // sum t
        part[(b * 3 + 2) * BLOCKS_X + blockIdx.x] = a2;  // sum p*t
    }
}

// One block, 4 waves; wave w reduces planes w, w+4, w+8 (<9); thread 0 finishes.
__global__ __launch_bounds__(256) void dice_final(
    const float* __restrict__ part /* [9][BLOCKS_X] */,
    const float* __restrict__ weight,
    float* __restrict__ out)
{
    __shared__ float sums[9];
    const int wave = threadIdx.x >> 6;
    const int lane = threadIdx.x & 63;

    for (int c9 = wave; c9 < 9; c9 += 4) {
        float s = 0.f;
        #pragma unroll
        for (int i = 0; i < BLOCKS_X / 64; ++i)     // 9 coalesced chunks
            s += part[c9 * BLOCKS_X + i * 64 + lane];
        #pragma unroll
        for (int off = 32; off > 0; off >>= 1)
            s += __shfl_down(s, off);
        if (lane == 0) sums[c9] = s;
    }
    __syncthreads();

    if (threadIdx.x == 0) {
        float loss = 0.f;
        #pragma unroll
        for (int bb = 0; bb < B_BATCH; ++bb) {
            float wgt  = weight[bb];
            float ssp  = sums[bb * 3 + 0];
            float sst  = sums[bb * 3 + 1];
            float sspt = sums[bb * 3 + 2];
            float dice = (2.f * sspt * wgt + 1.f) / ((ssp + sst) * wgt + 1.f);
            loss += 1.f - dice;
        }
        out[0] = loss / (float)B_BATCH;
    }
}

extern "C" void kernel_launch(void* const* d_in, const int* in_sizes, int n_in,
                              void* d_out, int out_size, void* d_ws, size_t ws_size,
                              hipStream_t stream) {
    const float* pred   = (const float*)d_in[0];
    const float* target = (const float*)d_in[1];
    const float* weight = (const float*)d_in[2];
    float* out  = (float*)d_out;
    float* part = (float*)d_ws;  // 9 * 576 * 4 = 20,736 bytes

    dim3 grid(BLOCKS_X, B_BATCH);
    dice_partial<<<grid, BLK, 0, stream>>>(pred, target, part);
    dice_final<<<1, 256, 0, stream>>>(part, weight, out);
}